// Round 20
// baseline (416.120 us; speedup 1.0000x reference)
//
#include <hip/hip_runtime.h>
#include <hip/hip_bf16.h>

// B=2, Tq=1024, Tk=4096, DIM=1024, H=16, Hd=64, SCALE=0.125
#define BATCH 2
#define TQ 1024
#define TK 4096
#define DIMSZ 1024
#define NH 16
#define HD 64
#define SCALE 0.125f

typedef __bf16 bf16x8 __attribute__((ext_vector_type(8)));
typedef float f32x4 __attribute__((ext_vector_type(4)));

// Native f32->bf16 (RTNE); pairs fuse into v_cvt_pk_bf16_f32.
static __device__ inline unsigned short f2bf(float x) {
  union { __bf16 h; unsigned short u; } v;
  v.h = (__bf16)x;
  return v.u;
}
static __device__ inline unsigned int pack2(float a, float b) {
  return (unsigned int)f2bf(a) | ((unsigned int)f2bf(b) << 16);
}

// ---------------------------------------------------------------------------
// One-shot cast of all f32 tensors to bf16. blockIdx.y picks the job.
// ---------------------------------------------------------------------------
__global__ __launch_bounds__(256) void cast_all(
    const float* __restrict__ q, const float* __restrict__ k,
    const float* __restrict__ v, const float* __restrict__ wq,
    const float* __restrict__ wk, const float* __restrict__ wv,
    const float* __restrict__ wo, unsigned short* __restrict__ qo,
    unsigned short* __restrict__ ko, unsigned short* __restrict__ vo,
    unsigned short* __restrict__ wqo, unsigned short* __restrict__ wko,
    unsigned short* __restrict__ wvo, unsigned short* __restrict__ woo) {
  const float* src;
  unsigned short* dst;
  long n;
  switch (blockIdx.y) {
    case 0: src = q;  dst = qo;  n = (long)BATCH * TQ * DIMSZ; break;
    case 1: src = k;  dst = ko;  n = (long)BATCH * TK * DIMSZ; break;
    case 2: src = v;  dst = vo;  n = (long)BATCH * TK * DIMSZ; break;
    case 3: src = wq; dst = wqo; n = (long)DIMSZ * DIMSZ; break;
    case 4: src = wk; dst = wko; n = (long)DIMSZ * DIMSZ; break;
    case 5: src = wv; dst = wvo; n = (long)DIMSZ * DIMSZ; break;
    default: src = wo; dst = woo; n = (long)DIMSZ * DIMSZ; break;
  }
  const long stride = (long)gridDim.x * 256 * 8;
  for (long i = ((long)blockIdx.x * 256 + threadIdx.x) * 8; i < n; i += stride) {
    const float4 a = *(const float4*)&src[i];
    const float4 b = *(const float4*)&src[i + 4];
    uint4 o;
    o.x = pack2(a.x, a.y);
    o.y = pack2(a.z, a.w);
    o.z = pack2(b.x, b.y);
    o.w = pack2(b.z, b.w);
    *(uint4*)&dst[i] = o;
  }
}

// ---------------------------------------------------------------------------
// Merged Q/K/V projection (m97-style): 128x128 tile, BK=32, 4 waves (2x2),
// linear LDS + global_load_lds width-16 staging.
// blockIdx.y 0..63 -> K, 64..127 -> V (epilogue writes TRANSPOSED head-
// slices directly to vT), 128..143 -> Q.
// ---------------------------------------------------------------------------
__global__ __launch_bounds__(256) void proj_qkv(
    const unsigned short* __restrict__ qbf, const unsigned short* __restrict__ kbf,
    const unsigned short* __restrict__ vbf, const unsigned short* __restrict__ wqb,
    const unsigned short* __restrict__ wkb, const unsigned short* __restrict__ wvb,
    const float* __restrict__ bq, const float* __restrict__ bk,
    const float* __restrict__ bv, unsigned short* __restrict__ qb,
    unsigned short* __restrict__ kb, unsigned short* __restrict__ vT) {
  __shared__ unsigned short As[128][32];
  __shared__ unsigned short Bs[128][32];
  __shared__ unsigned short T[64][132];  // V-transpose staging

  const int y = blockIdx.y;
  const unsigned short *A, *B;
  const float* bias;
  int row0;
  bool doT = false;
  unsigned short* Cout;
  if (y < 64) {
    A = kbf; B = wkb; bias = bk; Cout = kb; row0 = y * 128;
  } else if (y < 128) {
    A = vbf; B = wvb; bias = bv; Cout = vT; row0 = (y - 64) * 128; doT = true;
  } else {
    A = qbf; B = wqb; bias = bq; Cout = qb; row0 = (y - 128) * 128;
  }
  const int col0 = blockIdx.x * 128;
  const int K = DIMSZ, N = DIMSZ;

  const int t = threadIdx.x;
  const int lane = t & 63, wv = t >> 6;
  const int wm = wv >> 1, wn = wv & 1;
  const int l15 = lane & 15, l4 = lane >> 4;

  f32x4 acc[4][4];
#pragma unroll
  for (int i = 0; i < 4; i++)
#pragma unroll
    for (int j = 0; j < 4; j++) acc[i][j] = (f32x4){0.f, 0.f, 0.f, 0.f};

  const int grow = lane >> 2;
  const int gcol = (lane & 3) * 8;
  const unsigned short* pA = &A[(size_t)(row0 + wv * 32 + grow) * K + gcol];
  const unsigned short* pB = &B[(size_t)(col0 + wv * 32 + grow) * K + gcol];

  for (int k0 = 0; k0 < K; k0 += 32) {
    __syncthreads();
#pragma unroll
    for (int c = 0; c < 2; c++) {
      __builtin_amdgcn_global_load_lds(
          (const __attribute__((address_space(1))) unsigned int*)(
              pA + (size_t)(c * 16) * K + k0),
          (__attribute__((address_space(3))) unsigned int*)&As[wv * 32 + c * 16][0],
          16, 0, 0);
      __builtin_amdgcn_global_load_lds(
          (const __attribute__((address_space(1))) unsigned int*)(
              pB + (size_t)(c * 16) * K + k0),
          (__attribute__((address_space(3))) unsigned int*)&Bs[wv * 32 + c * 16][0],
          16, 0, 0);
    }
    __syncthreads();
    bf16x8 av[4], bv[4];
#pragma unroll
    for (int f = 0; f < 4; f++) {
      av[f] = *(const bf16x8*)&As[wm * 64 + f * 16 + l15][l4 * 8];
      bv[f] = *(const bf16x8*)&Bs[wn * 64 + f * 16 + l15][l4 * 8];
    }
#pragma unroll
    for (int fm = 0; fm < 4; fm++)
#pragma unroll
      for (int fn = 0; fn < 4; fn++)
        acc[fm][fn] = __builtin_amdgcn_mfma_f32_16x16x32_bf16(
            av[fm], bv[fn], acc[fm][fn], 0, 0, 0);
  }

  if (!doT) {
#pragma unroll
    for (int fm = 0; fm < 4; fm++) {
#pragma unroll
      for (int i = 0; i < 4; i++) {
        const int rr = row0 + wm * 64 + fm * 16 + l4 * 4 + i;
#pragma unroll
        for (int fn = 0; fn < 4; fn++) {
          const int c = col0 + wn * 64 + fn * 16 + l15;
          Cout[(size_t)rr * N + c] = f2bf(acc[fm][fn][i] + bias[c]);
        }
      }
    }
  } else {
    // V: write vT[(b*1024 + col)*TK + krow] via LDS transpose, 2 passes.
    const int bb = row0 >> 12;          // row0 / TK (batch)
    const int krow0 = row0 & (TK - 1);  // row within batch
#pragma unroll
    for (int pass = 0; pass < 2; pass++) {
      __syncthreads();
      if (wn == pass) {
#pragma unroll
        for (int fm = 0; fm < 4; fm++)
#pragma unroll
          for (int fn = 0; fn < 4; fn++)
#pragma unroll
            for (int i = 0; i < 4; i++) {
              const int cp = fn * 16 + l15;
              const int row = wm * 64 + fm * 16 + l4 * 4 + i;
              const int c = col0 + pass * 64 + cp;
              T[cp][row] = f2bf(acc[fm][fn][i] + bias[c]);
            }
      }
      __syncthreads();
#pragma unroll
      for (int qd = 0; qd < 4; qd++) {
        const int idx = t + qd * 256;     // 0..1023
        const int cp = idx >> 4;          // 0..63
        const int off8 = (idx & 15) * 8;  // 0..120
        const uint4 v = *(const uint4*)&T[cp][off8];
        *(uint4*)&vT[(size_t)(bb * 1024 + col0 + pass * 64 + cp) * TK +
                     krow0 + off8] = v;
      }
    }
  }
}

// Output projection (f32 out), m97-style body.
__global__ __launch_bounds__(256) void proj_o(
    const unsigned short* __restrict__ A, const unsigned short* __restrict__ B,
    const float* __restrict__ bias, float* __restrict__ C) {
  __shared__ unsigned short As[128][32];
  __shared__ unsigned short Bs[128][32];
  const int row0 = blockIdx.y * 128, col0 = blockIdx.x * 128;
  const int K = DIMSZ, N = DIMSZ;
  const int t = threadIdx.x;
  const int lane = t & 63, wv = t >> 6;
  const int wm = wv >> 1, wn = wv & 1;
  const int l15 = lane & 15, l4 = lane >> 4;

  f32x4 acc[4][4];
#pragma unroll
  for (int i = 0; i < 4; i++)
#pragma unroll
    for (int j = 0; j < 4; j++) acc[i][j] = (f32x4){0.f, 0.f, 0.f, 0.f};

  const int grow = lane >> 2;
  const int gcol = (lane & 3) * 8;
  const unsigned short* pA = &A[(size_t)(row0 + wv * 32 + grow) * K + gcol];
  const unsigned short* pB = &B[(size_t)(col0 + wv * 32 + grow) * K + gcol];

  for (int k0 = 0; k0 < K; k0 += 32) {
    __syncthreads();
#pragma unroll
    for (int c = 0; c < 2; c++) {
      __builtin_amdgcn_global_load_lds(
          (const __attribute__((address_space(1))) unsigned int*)(
              pA + (size_t)(c * 16) * K + k0),
          (__attribute__((address_space(3))) unsigned int*)&As[wv * 32 + c * 16][0],
          16, 0, 0);
      __builtin_amdgcn_global_load_lds(
          (const __attribute__((address_space(1))) unsigned int*)(
              pB + (size_t)(c * 16) * K + k0),
          (__attribute__((address_space(3))) unsigned int*)&Bs[wv * 32 + c * 16][0],
          16, 0, 0);
    }
    __syncthreads();
    bf16x8 av[4], bv[4];
#pragma unroll
    for (int f = 0; f < 4; f++) {
      av[f] = *(const bf16x8*)&As[wm * 64 + f * 16 + l15][l4 * 8];
      bv[f] = *(const bf16x8*)&Bs[wn * 64 + f * 16 + l15][l4 * 8];
    }
#pragma unroll
    for (int fm = 0; fm < 4; fm++)
#pragma unroll
      for (int fn = 0; fn < 4; fn++)
        acc[fm][fn] = __builtin_amdgcn_mfma_f32_16x16x32_bf16(
            av[fm], bv[fn], acc[fm][fn], 0, 0, 0);
  }

#pragma unroll
  for (int fm = 0; fm < 4; fm++) {
#pragma unroll
    for (int i = 0; i < 4; i++) {
      const int rr = row0 + wm * 64 + fm * 16 + l4 * 4 + i;
#pragma unroll
      for (int fn = 0; fn < 4; fn++) {
        const int c = col0 + wn * 64 + fn * 16 + l15;
        C[(size_t)rr * N + c] = acc[fm][fn][i] + bias[c];
      }
    }
  }
}

// ---------------------------------------------------------------------------
// Fused attention middle. Flat LDS pool: loop 1 views it as K256[256][68]
// (256-row K tiles, HALF the loop-1 barriers); loop 2 views it with R18's
// exact layout (Ks[128][72], Vs[64][140], Ps[64][136]) - loop-2 code
// unchanged. Qs separate. Per block = 64 q-rows of one (b,h).
// Grid: 1D 512 blocks, XCD-chunked swizzle.
// ---------------------------------------------------------------------------
__global__ __launch_bounds__(256) void attn_fused(
    const unsigned short* __restrict__ qb, const unsigned short* __restrict__ kb,
    const unsigned short* __restrict__ vT, float* __restrict__ attn,
    unsigned short* __restrict__ aout) {
  const int dsp = blockIdx.x;
  const int orig = (dsp & 7) * 64 + (dsp >> 3);
  const int z = orig >> 4, mb = orig & 15;
  const int b = z >> 4, h = z & 15;
  const int m0 = mb * 64;

  __shared__ unsigned short Qs[64][72];
  __shared__ unsigned short pool[26880];  // 53,760 B shared between loops
  __shared__ float partial[64][2];
  __shared__ float rinv[64];

  const int t = threadIdx.x;
  const int lane = t & 63, wid = t >> 6;
  const int wm = wid >> 1, wn = wid & 1;
  const int l15 = lane & 15, l4 = lane >> 4;

  const unsigned short* kb_z = kb + (size_t)b * TK * DIMSZ + h * HD;

  // stage Q [64][64]
#pragma unroll
  for (int p = 0; p < 2; p++) {
    const int idx = t + p * 256;
    const int r = idx >> 3, kc = idx & 7;
    *(uint4*)&Qs[r][kc * 8] =
        *(const uint4*)&qb[(size_t)(b * TQ + m0 + r) * DIMSZ + h * HD + kc * 8];
  }
  __syncthreads();
  bf16x8 aq[2][2];
#pragma unroll
  for (int fm = 0; fm < 2; fm++)
#pragma unroll
    for (int ks = 0; ks < 2; ks++)
      aq[fm][ks] = *(const bf16x8*)&Qs[wm * 32 + fm * 16 + l15][ks * 32 + l4 * 8];

  // ------------- Loop 1: row sums, 256-row K tiles (32 barriers) -----------
  float rsum[8];
#pragma unroll
  for (int r = 0; r < 8; r++) rsum[r] = 0.f;

  for (int kt = 0; kt < TK / 256; kt++) {
    __syncthreads();
    // stage K [256][64] into pool as [256][68]: 8 x uint4 per thread
#pragma unroll
    for (int p = 0; p < 8; p++) {
      const int idx = t + p * 256;
      const int r = idx >> 3, kc = idx & 7;
      *(uint4*)&pool[r * 68 + kc * 8] =
          *(const uint4*)&kb_z[(size_t)(kt * 256 + r) * DIMSZ + kc * 8];
    }
    __syncthreads();
#pragma unroll
    for (int half = 0; half < 2; half++) {
      bf16x8 bk_[4][2];
#pragma unroll
      for (int fn = 0; fn < 4; fn++)
#pragma unroll
        for (int ks = 0; ks < 2; ks++)
          bk_[fn][ks] = *(const bf16x8*)&pool[
              (half * 128 + wn * 64 + fn * 16 + l15) * 68 + ks * 32 + l4 * 8];
      f32x4 acc_s[2][4];
#pragma unroll
      for (int i = 0; i < 2; i++)
#pragma unroll
        for (int j = 0; j < 4; j++) acc_s[i][j] = (f32x4){0.f, 0.f, 0.f, 0.f};
#pragma unroll
      for (int ks = 0; ks < 2; ks++)
#pragma unroll
        for (int fm = 0; fm < 2; fm++)
#pragma unroll
          for (int fn = 0; fn < 4; fn++)
            acc_s[fm][fn] = __builtin_amdgcn_mfma_f32_16x16x32_bf16(
                aq[fm][ks], bk_[fn][ks], acc_s[fm][fn], 0, 0, 0);
#pragma unroll
      for (int fm = 0; fm < 2; fm++)
#pragma unroll
        for (int i = 0; i < 4; i++) {
          float s = 0.f;
#pragma unroll
          for (int fn = 0; fn < 4; fn++) s += __expf(acc_s[fm][fn][i] * SCALE);
          rsum[fm * 4 + i] += s;
        }
    }
  }
  // reduce over the 16 lanes of each row-group (l15)
#pragma unroll
  for (int off = 1; off < 16; off <<= 1)
#pragma unroll
    for (int r = 0; r < 8; r++) rsum[r] += __shfl_xor(rsum[r], off);
  if (l15 == 0) {
#pragma unroll
    for (int fm = 0; fm < 2; fm++)
#pragma unroll
      for (int i = 0; i < 4; i++)
        partial[wm * 32 + fm * 16 + l4 * 4 + i][wn] = rsum[fm * 4 + i];
  }
  __syncthreads();
  if (t < 64) rinv[t] = 1.f / (partial[t][0] + partial[t][1]);

  // ------------------ Loop 2: attn write + PV (R18 layout) ------------------
  unsigned short (*Ks)[72] = (unsigned short(*)[72])&pool[0];
  unsigned short (*Vs)[140] = (unsigned short(*)[140])&pool[9216];
  unsigned short (*Ps)[136] = (unsigned short(*)[136])&pool[9216 + 8960];

  f32x4 acc_o[4];
#pragma unroll
  for (int j = 0; j < 4; j++) acc_o[j] = (f32x4){0.f, 0.f, 0.f, 0.f};

  float* attn_z = attn + (size_t)z * TQ * TK;

  for (int kt = 0; kt < TK / 128; kt++) {
    __syncthreads();
    // stage K tile [128 k-rows][64 d]
#pragma unroll
    for (int p = 0; p < 4; p++) {
      const int idx = t + p * 256;
      const int r = idx >> 3, kc = idx & 7;
      *(uint4*)&Ks[r][kc * 8] =
          *(const uint4*)&kb_z[(size_t)(kt * 128 + r) * DIMSZ + kc * 8];
    }
    // stage V tile [64 d][128 k]
#pragma unroll
    for (int p = 0; p < 4; p++) {
      const int idx = t + p * 256;
      const int d = idx >> 4, kc = idx & 15;
      *(uint4*)&Vs[d][kc * 8] =
          *(const uint4*)&vT[(size_t)(z * HD + d) * TK + kt * 128 + kc * 8];
    }
    __syncthreads();

    // S tile [64][128]
    bf16x8 bk_[4][2];
#pragma unroll
    for (int fn = 0; fn < 4; fn++)
#pragma unroll
      for (int ks = 0; ks < 2; ks++)
        bk_[fn][ks] =
            *(const bf16x8*)&Ks[wn * 64 + fn * 16 + l15][ks * 32 + l4 * 8];
    f32x4 acc_s[2][4];
#pragma unroll
    for (int i = 0; i < 2; i++)
#pragma unroll
      for (int j = 0; j < 4; j++) acc_s[i][j] = (f32x4){0.f, 0.f, 0.f, 0.f};
#pragma unroll
    for (int ks = 0; ks < 2; ks++)
#pragma unroll
      for (int fm = 0; fm < 2; fm++)
#pragma unroll
        for (int fn = 0; fn < 4; fn++)
          acc_s[fm][fn] = __builtin_amdgcn_mfma_f32_16x16x32_bf16(
              aq[fm][ks], bk_[fn][ks], acc_s[fm][fn], 0, 0, 0);

    // normalize: nt-store attn directly from regs + park bf16 P in Ps
#pragma unroll
    for (int fm = 0; fm < 2; fm++)
#pragma unroll
      for (int i = 0; i < 4; i++) {
        const int row = wm * 32 + fm * 16 + l4 * 4 + i;
        const float iv = rinv[row];
        float* arow = &attn_z[(size_t)(m0 + row) * TK + kt * 128];
#pragma unroll
        for (int fn = 0; fn < 4; fn++) {
          const int col = wn * 64 + fn * 16 + l15;
          const float p = __expf(acc_s[fm][fn][i] * SCALE) * iv;
          __builtin_nontemporal_store(p, &arow[col]);
          Ps[row][col] = f2bf(p);
        }
      }
    __syncthreads();

    // O += P[64x128] @ V[128x64]
#pragma unroll
    for (int ks2 = 0; ks2 < 4; ks2++) {
      const bf16x8 ap = *(const bf16x8*)&Ps[wid * 16 + l15][ks2 * 32 + l4 * 8];
#pragma unroll
      for (int fn = 0; fn < 4; fn++) {
        const bf16x8 bvv =
            *(const bf16x8*)&Vs[fn * 16 + l15][ks2 * 32 + l4 * 8];
        acc_o[fn] = __builtin_amdgcn_mfma_f32_16x16x32_bf16(ap, bvv,
                                                            acc_o[fn], 0, 0, 0);
      }
    }
  }

#pragma unroll
  for (int fn = 0; fn < 4; fn++)
#pragma unroll
    for (int i = 0; i < 4; i++) {
      const int rr = m0 + wid * 16 + l4 * 4 + i;
      aout[(size_t)(b * TQ + rr) * DIMSZ + h * HD + fn * 16 + l15] =
          f2bf(acc_o[fn][i]);
    }
}

// ---------------------------------------------------------------------------
// Residual + LayerNorm (f32)
// ---------------------------------------------------------------------------
__global__ __launch_bounds__(256) void residual_ln(
    const float* __restrict__ q, const float* __restrict__ y,
    const float* __restrict__ gamma, const float* __restrict__ beta,
    float* __restrict__ out) {
  __shared__ float w1[4];
  __shared__ float w2[4];
  const size_t base = (size_t)blockIdx.x * DIMSZ;
  const int t = threadIdx.x;

  float x[4];
  float s = 0.f;
#pragma unroll
  for (int i = 0; i < 4; i++) {
    const int c = t + i * 256;
    x[i] = q[base + c] + y[base + c];
    s += x[i];
  }
#pragma unroll
  for (int off = 32; off; off >>= 1) s += __shfl_xor(s, off);
  if ((t & 63) == 0) w1[t >> 6] = s;
  __syncthreads();
  const float mean = (w1[0] + w1[1] + w1[2] + w1[3]) * (1.f / DIMSZ);

  float vs = 0.f;
#pragma unroll
  for (int i = 0; i < 4; i++) {
    const float d = x[i] - mean;
    vs += d * d;
  }
#pragma unroll
  for (int off = 32; off; off >>= 1) vs += __shfl_xor(vs, off);
  if ((t & 63) == 0) w2[t >> 6] = vs;
  __syncthreads();
  const float var = (w2[0] + w2[1] + w2[2] + w2[3]) * (1.f / DIMSZ);
  const float rstd = rsqrtf(var + 1e-5f);

#pragma unroll
  for (int i = 0; i < 4; i++) {
    const int c = t + i * 256;
    out[base + c] = (x[i] - mean) * rstd * gamma[c] + beta[c];
  }
}

// ---------------------------------------------------------------------------
extern "C" void kernel_launch(void* const* d_in, const int* in_sizes, int n_in,
                              void* d_out, int out_size, void* d_ws,
                              size_t ws_size, hipStream_t stream) {
  const float* query = (const float*)d_in[0];
  const float* key   = (const float*)d_in[1];
  const float* value = (const float*)d_in[2];
  const float* Wq = (const float*)d_in[3];
  const float* bq = (const float*)d_in[4];
  const float* Wk = (const float*)d_in[5];
  const float* bk = (const float*)d_in[6];
  const float* Wv = (const float*)d_in[7];
  const float* bv = (const float*)d_in[8];
  const float* Wo = (const float*)d_in[9];
  const float* bo = (const float*)d_in[10];
  const float* ln_gamma = (const float*)d_in[11];
  const float* ln_beta  = (const float*)d_in[12];

  float* out  = (float*)d_out;                    // [B, Tq, DIM] f32
  float* attn = out + (size_t)BATCH * TQ * DIMSZ; // [32, 1024, 4096] f32

  const size_t MQ = (size_t)BATCH * TQ * DIMSZ;   // 2M
  const size_t MK = (size_t)BATCH * TK * DIMSZ;   // 8M
  const size_t MM = (size_t)DIMSZ * DIMSZ;        // 1M

  unsigned short* ws = (unsigned short*)d_ws;
  unsigned short* qbf = ws;              // 4 MB  cast(query); later ab
  unsigned short* kbf = qbf + MQ;        // 16 MB cast(key)
  unsigned short* vbf = kbf + MK;        // 16 MB cast(value); later ybuf
  unsigned short* wqb = vbf + MK;        // 2 MB
  unsigned short* wkb = wqb + MM;        // 2 MB
  unsigned short* wvb = wkb + MM;        // 2 MB
  unsigned short* wob = wvb + MM;        // 2 MB
  unsigned short* qb  = wob + MM;        // 4 MB  Q proj out
  unsigned short* kb  = qb + MQ;         // 16 MB K proj out
  unsigned short* vT  = kb + MK;         // 16 MB V proj out (pre-transposed)
  // aliases (lifetimes audited):
  unsigned short* ab = qbf;  // attn head outputs (qbf dead after proj)
  float* ybuf = (float*)vbf; // O-proj out (vbf dead after proj)

  const dim3 blk(256);

  // Cast everything to bf16 once
  cast_all<<<dim3(1024, 7), blk, 0, stream>>>(query, key, value, Wq, Wk, Wv,
                                              Wo, qbf, kbf, vbf, wqb, wkb,
                                              wvb, wob);

  // Merged Q/K/V projections; V epilogue writes vT directly (transposed)
  proj_qkv<<<dim3(DIMSZ / 128, 144), blk, 0, stream>>>(
      qbf, kbf, vbf, wqb, wkb, wvb, bq, bk, bv, qb, kb, vT);

  // Fused attention middle (stats + normalize + attn write + PV)
  attn_fused<<<dim3(512), blk, 0, stream>>>(qb, kb, vT, attn, ab);

  // Output projection (f32 out)
  proj_o<<<dim3(DIMSZ / 128, (BATCH * TQ) / 128), blk, 0, stream>>>(ab, wob,
                                                                    bo, ybuf);

  residual_ln<<<dim3(BATCH * TQ), blk, 0, stream>>>(query, ybuf, ln_gamma,
                                                    ln_beta, out);
}

// Round 21
// 312.880 us; speedup vs baseline: 1.3300x; 1.3300x over previous
//
#include <hip/hip_runtime.h>
#include <hip/hip_bf16.h>

// B=2, Tq=1024, Tk=4096, DIM=1024, H=16, Hd=64, SCALE=0.125
#define BATCH 2
#define TQ 1024
#define TK 4096
#define DIMSZ 1024
#define NH 16
#define HD 64
#define SCALE 0.125f

typedef __bf16 bf16x8 __attribute__((ext_vector_type(8)));
typedef float f32x4 __attribute__((ext_vector_type(4)));

// Native f32->bf16 (RTNE); pairs fuse into v_cvt_pk_bf16_f32.
static __device__ inline unsigned short f2bf(float x) {
  union { __bf16 h; unsigned short u; } v;
  v.h = (__bf16)x;
  return v.u;
}
static __device__ inline unsigned int pack2(float a, float b) {
  return (unsigned int)f2bf(a) | ((unsigned int)f2bf(b) << 16);
}

// ---------------------------------------------------------------------------
// One-shot cast of all f32 tensors to bf16. blockIdx.y picks the job.
// ---------------------------------------------------------------------------
__global__ __launch_bounds__(256) void cast_all(
    const float* __restrict__ q, const float* __restrict__ k,
    const float* __restrict__ v, const float* __restrict__ wq,
    const float* __restrict__ wk, const float* __restrict__ wv,
    const float* __restrict__ wo, unsigned short* __restrict__ qo,
    unsigned short* __restrict__ ko, unsigned short* __restrict__ vo,
    unsigned short* __restrict__ wqo, unsigned short* __restrict__ wko,
    unsigned short* __restrict__ wvo, unsigned short* __restrict__ woo) {
  const float* src;
  unsigned short* dst;
  long n;
  switch (blockIdx.y) {
    case 0: src = q;  dst = qo;  n = (long)BATCH * TQ * DIMSZ; break;
    case 1: src = k;  dst = ko;  n = (long)BATCH * TK * DIMSZ; break;
    case 2: src = v;  dst = vo;  n = (long)BATCH * TK * DIMSZ; break;
    case 3: src = wq; dst = wqo; n = (long)DIMSZ * DIMSZ; break;
    case 4: src = wk; dst = wko; n = (long)DIMSZ * DIMSZ; break;
    case 5: src = wv; dst = wvo; n = (long)DIMSZ * DIMSZ; break;
    default: src = wo; dst = woo; n = (long)DIMSZ * DIMSZ; break;
  }
  const long stride = (long)gridDim.x * 256 * 8;
  for (long i = ((long)blockIdx.x * 256 + threadIdx.x) * 8; i < n; i += stride) {
    const float4 a = *(const float4*)&src[i];
    const float4 b = *(const float4*)&src[i + 4];
    uint4 o;
    o.x = pack2(a.x, a.y);
    o.y = pack2(a.z, a.w);
    o.z = pack2(b.x, b.y);
    o.w = pack2(b.z, b.w);
    *(uint4*)&dst[i] = o;
  }
}

// ---------------------------------------------------------------------------
// m97-style bf16 GEMM-NT body: 128x128 tile, BK=32, 4 waves (2x2),
// linear LDS + global_load_lds width-16 staging.
// C[m,n] = sum_k A[m,k]*B[n,k] + bias[n].
// ---------------------------------------------------------------------------
template <bool OUT_BF16>
static __device__ __forceinline__ void gemm_body(
    const unsigned short* __restrict__ A, const unsigned short* __restrict__ B,
    const float* __restrict__ bias, void* __restrict__ Cout, int N, int K,
    int row0, int col0) {
  __shared__ unsigned short As[128][32];
  __shared__ unsigned short Bs[128][32];
  const int t = threadIdx.x;
  const int lane = t & 63, wv = t >> 6;
  const int wm = wv >> 1, wn = wv & 1;
  const int l15 = lane & 15, l4 = lane >> 4;

  f32x4 acc[4][4];
#pragma unroll
  for (int i = 0; i < 4; i++)
#pragma unroll
    for (int j = 0; j < 4; j++) acc[i][j] = (f32x4){0.f, 0.f, 0.f, 0.f};

  const int grow = lane >> 2;
  const int gcol = (lane & 3) * 8;
  const unsigned short* pA = &A[(size_t)(row0 + wv * 32 + grow) * K + gcol];
  const unsigned short* pB = &B[(size_t)(col0 + wv * 32 + grow) * K + gcol];

  for (int k0 = 0; k0 < K; k0 += 32) {
    __syncthreads();
#pragma unroll
    for (int c = 0; c < 2; c++) {
      __builtin_amdgcn_global_load_lds(
          (const __attribute__((address_space(1))) unsigned int*)(
              pA + (size_t)(c * 16) * K + k0),
          (__attribute__((address_space(3))) unsigned int*)&As[wv * 32 + c * 16][0],
          16, 0, 0);
      __builtin_amdgcn_global_load_lds(
          (const __attribute__((address_space(1))) unsigned int*)(
              pB + (size_t)(c * 16) * K + k0),
          (__attribute__((address_space(3))) unsigned int*)&Bs[wv * 32 + c * 16][0],
          16, 0, 0);
    }
    __syncthreads();
    bf16x8 av[4], bv[4];
#pragma unroll
    for (int f = 0; f < 4; f++) {
      av[f] = *(const bf16x8*)&As[wm * 64 + f * 16 + l15][l4 * 8];
      bv[f] = *(const bf16x8*)&Bs[wn * 64 + f * 16 + l15][l4 * 8];
    }
#pragma unroll
    for (int fm = 0; fm < 4; fm++)
#pragma unroll
      for (int fn = 0; fn < 4; fn++)
        acc[fm][fn] = __builtin_amdgcn_mfma_f32_16x16x32_bf16(
            av[fm], bv[fn], acc[fm][fn], 0, 0, 0);
  }

#pragma unroll
  for (int fm = 0; fm < 4; fm++) {
#pragma unroll
    for (int i = 0; i < 4; i++) {
      const int rr = row0 + wm * 64 + fm * 16 + l4 * 4 + i;
#pragma unroll
      for (int fn = 0; fn < 4; fn++) {
        const int c = col0 + wn * 64 + fn * 16 + l15;
        const float val = acc[fm][fn][i] + bias[c];
        if (OUT_BF16)
          ((unsigned short*)Cout)[(size_t)rr * N + c] = f2bf(val);
        else
          ((float*)Cout)[(size_t)rr * N + c] = val;
      }
    }
  }
}

// Merged Q/K/V projection: blockIdx.y 0..63 -> K, 64..127 -> V, 128..143 -> Q.
__global__ __launch_bounds__(256) void proj_qkv(
    const unsigned short* __restrict__ qbf, const unsigned short* __restrict__ kbf,
    const unsigned short* __restrict__ vbf, const unsigned short* __restrict__ wqb,
    const unsigned short* __restrict__ wkb, const unsigned short* __restrict__ wvb,
    const float* __restrict__ bq, const float* __restrict__ bk,
    const float* __restrict__ bv, unsigned short* __restrict__ qb,
    unsigned short* __restrict__ kb, unsigned short* __restrict__ vbp) {
  const int y = blockIdx.y;
  const unsigned short *A, *B;
  const float* bias;
  unsigned short* C;
  int row0;
  if (y < 64) {
    A = kbf; B = wkb; bias = bk; C = kb; row0 = y * 128;
  } else if (y < 128) {
    A = vbf; B = wvb; bias = bv; C = vbp; row0 = (y - 64) * 128;
  } else {
    A = qbf; B = wqb; bias = bq; C = qb; row0 = (y - 128) * 128;
  }
  gemm_body<true>(A, B, bias, C, DIMSZ, DIMSZ, row0, blockIdx.x * 128);
}

// Output projection (f32 out).
__global__ __launch_bounds__(256) void proj_o(
    const unsigned short* __restrict__ A, const unsigned short* __restrict__ B,
    const float* __restrict__ bias, float* __restrict__ C) {
  gemm_body<false>(A, B, bias, C, DIMSZ, DIMSZ, blockIdx.y * 128,
                   blockIdx.x * 128);
}

// ---------------------------------------------------------------------------
// Transpose V head-slices: vT[z*64+d][k] = vb[b*TK+k][h*64+d], bf16.
// ---------------------------------------------------------------------------
__global__ __launch_bounds__(256) void transpose_v(
    const unsigned short* __restrict__ vb, unsigned short* __restrict__ vT) {
  const int z = blockIdx.z, b = z >> 4, h = z & 15;
  const int k0 = blockIdx.x * 64;
  __shared__ unsigned short Ts[64][68];
  const int t = threadIdx.x;
  const int c4 = (t & 15) * 4, r = t >> 4;
#pragma unroll
  for (int p = 0; p < 4; p++) {
    const int rr = r + p * 16;
    *(uint2*)&Ts[rr][c4] =
        *(const uint2*)&vb[(size_t)(b * TK + k0 + rr) * DIMSZ + h * HD + c4];
  }
  __syncthreads();
#pragma unroll
  for (int p = 0; p < 4; p++) {
    const int c2 = t + p * 256;
    const int d = c2 >> 4, k4 = (c2 & 15) * 4;
    uint2 o;
    o.x = (unsigned int)Ts[k4][d] | ((unsigned int)Ts[k4 + 1][d] << 16);
    o.y = (unsigned int)Ts[k4 + 2][d] | ((unsigned int)Ts[k4 + 3][d] << 16);
    *(uint2*)&vT[(size_t)(z * HD + d) * TK + k0 + k4] = o;
  }
}

// ---------------------------------------------------------------------------
// Fused attention middle (R14-proven, best measured 313.3 us): per block =
// 64 q-rows of one (b,h).
// Loop 1: staged K, recompute S via MFMA, per-row sum(exp(SCALE*s)).
// Loop 2: staged K/V; p = exp*inv; nt-store attn from regs; park bf16 P in
//         Ps; PV from Ps/Vs.
// Grid: 1D 512 blocks, XCD-chunked swizzle. 2 blocks/CU (62 KB LDS).
// ---------------------------------------------------------------------------
__global__ __launch_bounds__(256) void attn_fused(
    const unsigned short* __restrict__ qb, const unsigned short* __restrict__ kb,
    const unsigned short* __restrict__ vT, float* __restrict__ attn,
    unsigned short* __restrict__ aout) {
  const int dsp = blockIdx.x;
  const int orig = (dsp & 7) * 64 + (dsp >> 3);
  const int z = orig >> 4, mb = orig & 15;
  const int b = z >> 4, h = z & 15;
  const int m0 = mb * 64;

  __shared__ unsigned short Qs[64][72];
  __shared__ unsigned short Ks[128][72];
  __shared__ unsigned short Vs[64][140];
  __shared__ unsigned short Ps[64][136];
  __shared__ float partial[64][2];
  __shared__ float rinv[64];

  const int t = threadIdx.x;
  const int lane = t & 63, wid = t >> 6;
  const int wm = wid >> 1, wn = wid & 1;
  const int l15 = lane & 15, l4 = lane >> 4;

  // stage Q [64][64]
#pragma unroll
  for (int p = 0; p < 2; p++) {
    const int idx = t + p * 256;
    const int r = idx >> 3, kc = idx & 7;
    *(uint4*)&Qs[r][kc * 8] =
        *(const uint4*)&qb[(size_t)(b * TQ + m0 + r) * DIMSZ + h * HD + kc * 8];
  }
  __syncthreads();
  bf16x8 aq[2][2];
#pragma unroll
  for (int fm = 0; fm < 2; fm++)
#pragma unroll
    for (int ks = 0; ks < 2; ks++)
      aq[fm][ks] = *(const bf16x8*)&Qs[wm * 32 + fm * 16 + l15][ks * 32 + l4 * 8];

  // ------------------ Loop 1: row sums ------------------
  float rsum[8];
#pragma unroll
  for (int r = 0; r < 8; r++) rsum[r] = 0.f;

  for (int kt = 0; kt < TK / 128; kt++) {
    __syncthreads();
#pragma unroll
    for (int p = 0; p < 4; p++) {
      const int idx = t + p * 256;
      const int r = idx >> 3, kc = idx & 7;
      *(uint4*)&Ks[r][kc * 8] = *(const uint4*)&kb[
          (size_t)(b * TK + kt * 128 + r) * DIMSZ + h * HD + kc * 8];
    }
    __syncthreads();
    bf16x8 bk_[4][2];
#pragma unroll
    for (int fn = 0; fn < 4; fn++)
#pragma unroll
      for (int ks = 0; ks < 2; ks++)
        bk_[fn][ks] =
            *(const bf16x8*)&Ks[wn * 64 + fn * 16 + l15][ks * 32 + l4 * 8];
    f32x4 acc_s[2][4];
#pragma unroll
    for (int i = 0; i < 2; i++)
#pragma unroll
      for (int j = 0; j < 4; j++) acc_s[i][j] = (f32x4){0.f, 0.f, 0.f, 0.f};
#pragma unroll
    for (int ks = 0; ks < 2; ks++)
#pragma unroll
      for (int fm = 0; fm < 2; fm++)
#pragma unroll
        for (int fn = 0; fn < 4; fn++)
          acc_s[fm][fn] = __builtin_amdgcn_mfma_f32_16x16x32_bf16(
              aq[fm][ks], bk_[fn][ks], acc_s[fm][fn], 0, 0, 0);
#pragma unroll
    for (int fm = 0; fm < 2; fm++)
#pragma unroll
      for (int i = 0; i < 4; i++) {
        float s = 0.f;
#pragma unroll
        for (int fn = 0; fn < 4; fn++) s += __expf(acc_s[fm][fn][i] * SCALE);
        rsum[fm * 4 + i] += s;
      }
  }
  // reduce over the 16 lanes of each row-group (l15)
#pragma unroll
  for (int off = 1; off < 16; off <<= 1)
#pragma unroll
    for (int r = 0; r < 8; r++) rsum[r] += __shfl_xor(rsum[r], off);
  if (l15 == 0) {
#pragma unroll
    for (int fm = 0; fm < 2; fm++)
#pragma unroll
      for (int i = 0; i < 4; i++)
        partial[wm * 32 + fm * 16 + l4 * 4 + i][wn] = rsum[fm * 4 + i];
  }
  __syncthreads();
  if (t < 64) rinv[t] = 1.f / (partial[t][0] + partial[t][1]);

  // ------------------ Loop 2: attn write + PV ------------------
  f32x4 acc_o[4];
#pragma unroll
  for (int j = 0; j < 4; j++) acc_o[j] = (f32x4){0.f, 0.f, 0.f, 0.f};

  float* attn_z = attn + (size_t)z * TQ * TK;

  for (int kt = 0; kt < TK / 128; kt++) {
    __syncthreads();
    // stage K tile [128 k-rows][64 d]
#pragma unroll
    for (int p = 0; p < 4; p++) {
      const int idx = t + p * 256;
      const int r = idx >> 3, kc = idx & 7;
      *(uint4*)&Ks[r][kc * 8] = *(const uint4*)&kb[
          (size_t)(b * TK + kt * 128 + r) * DIMSZ + h * HD + kc * 8];
    }
    // stage V tile [64 d][128 k]
#pragma unroll
    for (int p = 0; p < 4; p++) {
      const int idx = t + p * 256;
      const int d = idx >> 4, kc = idx & 15;
      *(uint4*)&Vs[d][kc * 8] =
          *(const uint4*)&vT[(size_t)(z * HD + d) * TK + kt * 128 + kc * 8];
    }
    __syncthreads();

    // S tile [64][128]
    bf16x8 bk_[4][2];
#pragma unroll
    for (int fn = 0; fn < 4; fn++)
#pragma unroll
      for (int ks = 0; ks < 2; ks++)
        bk_[fn][ks] =
            *(const bf16x8*)&Ks[wn * 64 + fn * 16 + l15][ks * 32 + l4 * 8];
    f32x4 acc_s[2][4];
#pragma unroll
    for (int i = 0; i < 2; i++)
#pragma unroll
      for (int j = 0; j < 4; j++) acc_s[i][j] = (f32x4){0.f, 0.f, 0.f, 0.f};
#pragma unroll
    for (int ks = 0; ks < 2; ks++)
#pragma unroll
      for (int fm = 0; fm < 2; fm++)
#pragma unroll
        for (int fn = 0; fn < 4; fn++)
          acc_s[fm][fn] = __builtin_amdgcn_mfma_f32_16x16x32_bf16(
              aq[fm][ks], bk_[fn][ks], acc_s[fm][fn], 0, 0, 0);

    // normalize: nt-store attn directly from regs + park bf16 P in Ps
#pragma unroll
    for (int fm = 0; fm < 2; fm++)
#pragma unroll
      for (int i = 0; i < 4; i++) {
        const int row = wm * 32 + fm * 16 + l4 * 4 + i;
        const float iv = rinv[row];
        float* arow = &attn_z[(size_t)(m0 + row) * TK + kt * 128];
#pragma unroll
        for (int fn = 0; fn < 4; fn++) {
          const int col = wn * 64 + fn * 16 + l15;
          const float p = __expf(acc_s[fm][fn][i] * SCALE) * iv;
          __builtin_nontemporal_store(p, &arow[col]);
          Ps[row][col] = f2bf(p);
        }
      }
    __syncthreads();

    // O += P[64x128] @ V[128x64]
#pragma unroll
    for (int ks2 = 0; ks2 < 4; ks2++) {
      const bf16x8 ap = *(const bf16x8*)&Ps[wid * 16 + l15][ks2 * 32 + l4 * 8];
#pragma unroll
      for (int fn = 0; fn < 4; fn++) {
        const bf16x8 bvv =
            *(const bf16x8*)&Vs[fn * 16 + l15][ks2 * 32 + l4 * 8];
        acc_o[fn] = __builtin_amdgcn_mfma_f32_16x16x32_bf16(ap, bvv,
                                                            acc_o[fn], 0, 0, 0);
      }
    }
  }

#pragma unroll
  for (int fn = 0; fn < 4; fn++)
#pragma unroll
    for (int i = 0; i < 4; i++) {
      const int rr = m0 + wid * 16 + l4 * 4 + i;
      aout[(size_t)(b * TQ + rr) * DIMSZ + h * HD + fn * 16 + l15] =
          f2bf(acc_o[fn][i]);
    }
}

// ---------------------------------------------------------------------------
// Residual + LayerNorm (f32)
// ---------------------------------------------------------------------------
__global__ __launch_bounds__(256) void residual_ln(
    const float* __restrict__ q, const float* __restrict__ y,
    const float* __restrict__ gamma, const float* __restrict__ beta,
    float* __restrict__ out) {
  __shared__ float w1[4];
  __shared__ float w2[4];
  const size_t base = (size_t)blockIdx.x * DIMSZ;
  const int t = threadIdx.x;

  float x[4];
  float s = 0.f;
#pragma unroll
  for (int i = 0; i < 4; i++) {
    const int c = t + i * 256;
    x[i] = q[base + c] + y[base + c];
    s += x[i];
  }
#pragma unroll
  for (int off = 32; off; off >>= 1) s += __shfl_xor(s, off);
  if ((t & 63) == 0) w1[t >> 6] = s;
  __syncthreads();
  const float mean = (w1[0] + w1[1] + w1[2] + w1[3]) * (1.f / DIMSZ);

  float vs = 0.f;
#pragma unroll
  for (int i = 0; i < 4; i++) {
    const float d = x[i] - mean;
    vs += d * d;
  }
#pragma unroll
  for (int off = 32; off; off >>= 1) vs += __shfl_xor(vs, off);
  if ((t & 63) == 0) w2[t >> 6] = vs;
  __syncthreads();
  const float var = (w2[0] + w2[1] + w2[2] + w2[3]) * (1.f / DIMSZ);
  const float rstd = rsqrtf(var + 1e-5f);

#pragma unroll
  for (int i = 0; i < 4; i++) {
    const int c = t + i * 256;
    out[base + c] = (x[i] - mean) * rstd * gamma[c] + beta[c];
  }
}

// ---------------------------------------------------------------------------
extern "C" void kernel_launch(void* const* d_in, const int* in_sizes, int n_in,
                              void* d_out, int out_size, void* d_ws,
                              size_t ws_size, hipStream_t stream) {
  const float* query = (const float*)d_in[0];
  const float* key   = (const float*)d_in[1];
  const float* value = (const float*)d_in[2];
  const float* Wq = (const float*)d_in[3];
  const float* bq = (const float*)d_in[4];
  const float* Wk = (const float*)d_in[5];
  const float* bk = (const float*)d_in[6];
  const float* Wv = (const float*)d_in[7];
  const float* bv = (const float*)d_in[8];
  const float* Wo = (const float*)d_in[9];
  const float* bo = (const float*)d_in[10];
  const float* ln_gamma = (const float*)d_in[11];
  const float* ln_beta  = (const float*)d_in[12];

  float* out  = (float*)d_out;                    // [B, Tq, DIM] f32
  float* attn = out + (size_t)BATCH * TQ * DIMSZ; // [32, 1024, 4096] f32

  const size_t MQ = (size_t)BATCH * TQ * DIMSZ;   // 2M
  const size_t MK = (size_t)BATCH * TK * DIMSZ;   // 8M
  const size_t MM = (size_t)DIMSZ * DIMSZ;        // 1M

  unsigned short* ws = (unsigned short*)d_ws;
  unsigned short* qbf = ws;              // 4 MB  cast(query); later ab
  unsigned short* kbf = qbf + MQ;        // 16 MB cast(key);   later vT
  unsigned short* vbf = kbf + MK;        // 16 MB cast(value); later ybuf
  unsigned short* wqb = vbf + MK;        // 2 MB
  unsigned short* wkb = wqb + MM;        // 2 MB
  unsigned short* wvb = wkb + MM;        // 2 MB
  unsigned short* wob = wvb + MM;        // 2 MB
  unsigned short* qb  = wob + MM;        // 4 MB  Q proj out
  unsigned short* kb  = qb + MQ;         // 16 MB K proj out
  unsigned short* vbp = kb + MK;         // 16 MB V proj out
  // aliases (lifetimes audited):
  unsigned short* vT = kbf;  // written by transpose_v after proj (kbf dead)
  unsigned short* ab = qbf;  // attn head outputs (qbf dead after proj)
  float* ybuf = (float*)vbf; // O-proj out (vbf dead after proj)

  const dim3 blk(256);

  // Cast everything to bf16 once
  cast_all<<<dim3(1024, 7), blk, 0, stream>>>(query, key, value, Wq, Wk, Wv,
                                              Wo, qbf, kbf, vbf, wqb, wkb,
                                              wvb, wob);

  // Merged Q/K/V projections (K: y 0..63, V: 64..127, Q: 128..143)
  proj_qkv<<<dim3(DIMSZ / 128, 144), blk, 0, stream>>>(
      qbf, kbf, vbf, wqb, wkb, wvb, bq, bk, bv, qb, kb, vbp);

  // V transpose to [z][64][4096]
  transpose_v<<<dim3(TK / 64, 1, BATCH * NH), blk, 0, stream>>>(vbp, vT);

  // Fused attention middle (stats + normalize + attn write + PV)
  attn_fused<<<dim3(512), blk, 0, stream>>>(qb, kb, vT, attn, ab);

  // Output projection (f32 out)
  proj_o<<<dim3(DIMSZ / 128, (BATCH * TQ) / 128), blk, 0, stream>>>(ab, wob,
                                                                    bo, ybuf);

  residual_ln<<<dim3(BATCH * TQ), blk, 0, stream>>>(query, ybuf, ln_gamma,
                                                    ln_beta, out);
}